// Round 4
// baseline (669.597 us; speedup 1.0000x reference)
//
#include <hip/hip_runtime.h>
#include <hip/hip_bf16.h>
#include <math.h>

// Problem constants
#define DI   1024
#define EI   8
#define HI   4096
#define NI   4096   // B*T

typedef __bf16 bf16x8 __attribute__((ext_vector_type(8)));
typedef float  f32x4  __attribute__((ext_vector_type(4)));

// ---------- helpers ----------
__device__ __forceinline__ unsigned short f2bf(float f) {
  union { float f; unsigned u; } c; c.f = f;
  unsigned r = c.u + 0x7FFF + ((c.u >> 16) & 1);   // RNE
  return (unsigned short)(r >> 16);
}

// async global->LDS, 16B per lane; lds base must be wave-uniform
__device__ __forceinline__ void async16(const void* g, void* l) {
  __builtin_amdgcn_global_load_lds(
      (const __attribute__((address_space(1))) void*)g,
      (__attribute__((address_space(3))) void*)l, 16, 0, 0);
}

// tanh-approx GELU (max abs err ~3e-3 vs exact erf form)
__device__ __forceinline__ float gelu_f(float x) {
  const float u = x * (0.7978845608f + 0.0356774081f * x * x);
  const float tt = __expf(-2.0f * fabsf(u));
  float th = (1.0f - tt) / (1.0f + tt);
  th = copysignf(th, u);
  return 0.5f * x * (1.0f + th);
}

// ---------- LN + router body (one wave per token) ----------
__device__ __forceinline__ void ln_router_body(
    const float* __restrict__ x, const float* __restrict__ gamma,
    const float* __restrict__ beta, const float* __restrict__ gw,
    unsigned short* __restrict__ xnbf, float* __restrict__ probs_out,
    int* __restrict__ pairs, float2* __restrict__ gates2, int blk, int t)
{
  const int lane = t & 63, wid = t >> 6;
  const int n = blk * 4 + wid;

  const float4* xr = (const float4*)(x + (size_t)n * DI);
  float4 v[4];
  #pragma unroll
  for (int j = 0; j < 4; j++) v[j] = xr[lane * 4 + j];

  float s = 0.f, q = 0.f;
  #pragma unroll
  for (int j = 0; j < 4; j++) {
    s += v[j].x + v[j].y + v[j].z + v[j].w;
    q += v[j].x * v[j].x + v[j].y * v[j].y + v[j].z * v[j].z + v[j].w * v[j].w;
  }
  #pragma unroll
  for (int off = 1; off < 64; off <<= 1) {
    s += __shfl_xor(s, off);
    q += __shfl_xor(q, off);
  }
  const float mu = s * (1.0f / DI);
  const float rs = rsqrtf(q * (1.0f / DI) - mu * mu + 1e-5f);

  const float4* gr = (const float4*)gamma;
  const float4* br = (const float4*)beta;
  float xl[16];
  #pragma unroll
  for (int j = 0; j < 4; j++) {
    const float4 g4 = gr[lane * 4 + j];
    const float4 b4 = br[lane * 4 + j];
    xl[4 * j + 0] = (v[j].x - mu) * rs * g4.x + b4.x;
    xl[4 * j + 1] = (v[j].y - mu) * rs * g4.y + b4.y;
    xl[4 * j + 2] = (v[j].z - mu) * rs * g4.z + b4.z;
    xl[4 * j + 3] = (v[j].w - mu) * rs * g4.w + b4.w;
  }
  unsigned u[8];
  #pragma unroll
  for (int j = 0; j < 8; j++)
    u[j] = (unsigned)f2bf(xl[2 * j]) | ((unsigned)f2bf(xl[2 * j + 1]) << 16);
  uint4* dst = (uint4*)(xnbf + (size_t)n * DI + lane * 16);
  uint4 d0; d0.x = u[0]; d0.y = u[1]; d0.z = u[2]; d0.w = u[3];
  uint4 d1; d1.x = u[4]; d1.y = u[5]; d1.z = u[6]; d1.w = u[7];
  dst[0] = d0; dst[1] = d1;

  float p[8];
  #pragma unroll
  for (int e = 0; e < 8; e++) p[e] = 0.f;
  #pragma unroll
  for (int j = 0; j < 16; j++) {
    const float4* grow = (const float4*)(gw + (size_t)(lane * 16 + j) * EI);
    const float4 ga = grow[0], gb = grow[1];
    const float xv = xl[j];
    p[0] += xv * ga.x; p[1] += xv * ga.y; p[2] += xv * ga.z; p[3] += xv * ga.w;
    p[4] += xv * gb.x; p[5] += xv * gb.y; p[6] += xv * gb.z; p[7] += xv * gb.w;
  }
  #pragma unroll
  for (int e = 0; e < 8; e++)
    #pragma unroll
    for (int off = 1; off < 64; off <<= 1) p[e] += __shfl_xor(p[e], off);

  if (lane == 0) {
    float pm = -1e30f;
    #pragma unroll
    for (int e = 0; e < 8; e++) pm = fmaxf(pm, p[e]);
    float pr[8], ps = 0.f;
    #pragma unroll
    for (int e = 0; e < 8; e++) { pr[e] = expf(p[e] - pm); ps += pr[e]; }
    const float inv = 1.0f / ps;
    #pragma unroll
    for (int e = 0; e < 8; e++) {
      pr[e] *= inv;
      probs_out[(size_t)n * EI + e] = pr[e];
    }
    int i0 = 0; float m0 = pr[0];
    #pragma unroll
    for (int e = 1; e < 8; e++) if (pr[e] > m0) { m0 = pr[e]; i0 = e; }
    int i1 = -1; float m1 = -1e30f;
    #pragma unroll
    for (int e = 0; e < 8; e++) if (e != i0 && pr[e] > m1) { m1 = pr[e]; i1 = e; }
    const float ssum = m0 + m1 + 1e-8f;
    pairs[n] = i0 | (i1 << 8);
    float2 g2; g2.x = m0 / ssum; g2.y = m1 / ssum;
    gates2[n] = g2;
  }
}

// ---------- transpose body: fp32 (R,C) -> bf16 (C,R) 64x64 tile ----------
__device__ __forceinline__ void transpose_body(
    const float* __restrict__ in, unsigned short* __restrict__ out,
    int R, int C, int bx, int by, int bz, float (*tile)[65], int t)
{
  const size_t eoff = (size_t)bz * (size_t)R * (size_t)C;
  const int c0 = bx * 64, r0 = by * 64;
  {
    const int col = (t & 15) * 4;
    #pragma unroll
    for (int ii = 0; ii < 4; ii++) {
      const int row = (t >> 4) + ii * 16;
      const float4 v = *(const float4*)(in + eoff + (size_t)(r0 + row) * C + c0 + col);
      tile[row][col + 0] = v.x; tile[row][col + 1] = v.y;
      tile[row][col + 2] = v.z; tile[row][col + 3] = v.w;
    }
  }
  __syncthreads();
  {
    const int grp = t & 7;
    #pragma unroll
    for (int jj = 0; jj < 2; jj++) {
      const int orow = (t >> 3) + jj * 32;
      unsigned short vs[8];
      #pragma unroll
      for (int u = 0; u < 8; u++) vs[u] = f2bf(tile[grp * 8 + u][orow]);
      uint4 pk;
      pk.x = (unsigned)vs[0] | ((unsigned)vs[1] << 16);
      pk.y = (unsigned)vs[2] | ((unsigned)vs[3] << 16);
      pk.z = (unsigned)vs[4] | ((unsigned)vs[5] << 16);
      pk.w = (unsigned)vs[6] | ((unsigned)vs[7] << 16);
      *(uint4*)(out + eoff + (size_t)(c0 + orow) * R + r0 + grp * 8) = pk;
    }
  }
}

// ---------- kernel 1: fused prep — LN/router + w1 transpose + w2 transpose ----------
// blocks [0,1024): LN; [1024, 9216): w1T (grid 64x16x8); [9216, 17408): w2T (16x64x8)
__global__ __launch_bounds__(256) void prep_k(
    const float* __restrict__ x, const float* __restrict__ gamma,
    const float* __restrict__ beta, const float* __restrict__ gw,
    unsigned short* __restrict__ xnbf, float* __restrict__ probs_out,
    int* __restrict__ pairs, float2* __restrict__ gates2,
    const float* __restrict__ w1, unsigned short* __restrict__ w1t,
    const float* __restrict__ w2, unsigned short* __restrict__ w2t)
{
  __shared__ float tile[64][65];
  const int bx = blockIdx.x, t = threadIdx.x;
  if (bx < 1024) {
    ln_router_body(x, gamma, beta, gw, xnbf, probs_out, pairs, gates2, bx, t);
  } else if (bx < 1024 + 8192) {
    const int b = bx - 1024;                       // w1 (R=DI, C=HI), grid (64,16,8)
    transpose_body(w1, w1t, DI, HI, b & 63, (b >> 6) & 15, b >> 10, tile, t);
  } else {
    const int b = bx - 9216;                       // w2 (R=HI, C=DI), grid (16,64,8)
    transpose_body(w2, w2t, HI, DI, b & 15, (b >> 4) & 63, b >> 10, tile, t);
  }
}

// standalone transpose (fallback scheduling when ws is small)
__global__ __launch_bounds__(256) void transpose_cvt_k(
    const float* __restrict__ in, unsigned short* __restrict__ out, int R, int C)
{
  __shared__ float tile[64][65];
  transpose_body(in, out, R, C, blockIdx.x, blockIdx.y, blockIdx.z, tile, threadIdx.x);
}

// ---------- kernel 2: build compact per-expert lists + balance loss (1 block) ----------
__global__ __launch_bounds__(1024) void build_lists_k(
    const int* __restrict__ pairs, const float2* __restrict__ gates2,
    const float* __restrict__ probs, int* __restrict__ counts,
    int* __restrict__ offs, int* __restrict__ tok_list,
    float* __restrict__ gate_list, int2* __restrict__ ipos,
    float* __restrict__ out_bal)
{
  __shared__ int cnt[8];
  __shared__ int cur[8];
  __shared__ float wps[16][8];
  __shared__ float ps[8];
  const int t = threadIdx.x, lane = t & 63, wid = t >> 6;
  if (t < 8) cnt[t] = 0;
  __syncthreads();

  float acc[8];
  #pragma unroll
  for (int e = 0; e < 8; e++) acc[e] = 0.f;
  for (int n = t; n < NI; n += 1024) {
    const int pr = pairs[n];
    atomicAdd(&cnt[pr & 255], 1);
    atomicAdd(&cnt[pr >> 8], 1);
    const float4* prow = (const float4*)(probs + (size_t)n * EI);
    const float4 a = prow[0], b = prow[1];
    acc[0] += a.x; acc[1] += a.y; acc[2] += a.z; acc[3] += a.w;
    acc[4] += b.x; acc[5] += b.y; acc[6] += b.z; acc[7] += b.w;
  }
  #pragma unroll
  for (int e = 0; e < 8; e++)
    #pragma unroll
    for (int off = 1; off < 64; off <<= 1) acc[e] += __shfl_xor(acc[e], off);
  if (lane == 0)
    #pragma unroll
    for (int e = 0; e < 8; e++) wps[wid][e] = acc[e];
  __syncthreads();
  if (t < 8) {
    float sm = 0.f;
    for (int w = 0; w < 16; w++) sm += wps[w][t];
    ps[t] = sm;
  }
  __syncthreads();
  if (t == 0) {
    int off = 0; float bl = 0.f;
    for (int e = 0; e < 8; e++) {
      offs[e] = off; cur[e] = off; counts[e] = cnt[e];
      bl += (float)cnt[e] * ps[e];
      off += cnt[e];
    }
    *out_bal = 0.01f * 8.0f * bl / ((float)NI * (float)NI);
  }
  __syncthreads();
  for (int n = t; n < NI; n += 1024) {
    const int pr = pairs[n];
    const float2 g = gates2[n];
    const int p0 = atomicAdd(&cur[pr & 255], 1);
    tok_list[p0] = n; gate_list[p0] = g.x;
    const int p1 = atomicAdd(&cur[pr >> 8], 1);
    tok_list[p1] = n; gate_list[p1] = g.y;
    int2 ip; ip.x = p0; ip.y = p1;
    ipos[n] = ip;
  }
}

// ---------- kernel: residual init out = x (fallback path only) ----------
__global__ __launch_bounds__(256) void copy_x_k(const float* __restrict__ x, float* __restrict__ out)
{
  const size_t i = (size_t)blockIdx.x * 256 + threadIdx.x;
  ((float4*)out)[i] = ((const float4*)x)[i];
}

// ---------- kernel 3: grouped GEMM1 + bias + GELU -> h (bf16) ----------
// BM=256 (tokens), BN=256 (H), BK=64; 512 threads, 8 waves (2m x 4n), wave tile 128x64
__global__ __launch_bounds__(512, 2) void ffn1_k(
    const unsigned short* __restrict__ xnbf, const unsigned short* __restrict__ w1t,
    const float* __restrict__ b1, unsigned short* __restrict__ hbuf,
    const int* __restrict__ tok_list, const int* __restrict__ counts,
    const int* __restrict__ offsets)
{
  const int e = blockIdx.z;
  const int cnt = counts[e];
  const int mt = blockIdx.y;
  if (mt * 256 >= cnt) return;
  const int n0 = blockIdx.x * 256;
  const int t = threadIdx.x, lane = t & 63, w = t >> 6;
  const int wm = w & 1, wn = w >> 1;
  __shared__ __align__(16) unsigned short As[256 * 64];  // XOR(row&7) chunk swizzle
  __shared__ __align__(16) unsigned short Bs[256 * 64];

  const int sub = lane >> 3;
  const int kc = ((lane & 7) ^ sub) * 8;
  const int eoff = offsets[e];
  const unsigned short* baseA[4];
  const unsigned short* baseB[4];
  #pragma unroll
  for (int r = 0; r < 4; r++) {
    int row = (w << 5) + r * 8 + sub;            // 0..255 across 8 waves
    int idx = mt * 256 + row; if (idx > cnt - 1) idx = cnt - 1;
    int tok = tok_list[eoff + idx];
    baseA[r] = xnbf + (size_t)tok * DI + kc;
    baseB[r] = w1t + (size_t)e * HI * DI + (size_t)(n0 + row) * DI + kc;
  }

  f32x4 acc[8][4];
  const f32x4 zz = {0.f, 0.f, 0.f, 0.f};
  #pragma unroll
  for (int i = 0; i < 8; i++)
    #pragma unroll
    for (int j = 0; j < 4; j++) acc[i][j] = zz;

  const int mrow = (wm << 7) + (lane & 15);
  const int nrow = (wn << 6) + (lane & 15);
  const int ksw[2] = { ((lane >> 4) ^ (lane & 7)) * 8,
                       (((lane >> 4) + 4) ^ (lane & 7)) * 8 };

  for (int k0 = 0; k0 < DI; k0 += 64) {
    __syncthreads();
    #pragma unroll
    for (int r = 0; r < 4; r++) {
      async16(baseA[r] + k0, &As[((w << 5) + r * 8) * 64]);
      async16(baseB[r] + k0, &Bs[((w << 5) + r * 8) * 64]);
    }
    __syncthreads();
    #pragma unroll
    for (int kk = 0; kk < 2; kk++) {
      const int ko = ksw[kk];
      bf16x8 af[8], bfr[4];
      #pragma unroll
      for (int mi = 0; mi < 8; mi++)
        af[mi] = *(const bf16x8*)&As[(mrow + mi * 16) * 64 + ko];
      #pragma unroll
      for (int ni = 0; ni < 4; ni++)
        bfr[ni] = *(const bf16x8*)&Bs[(nrow + ni * 16) * 64 + ko];
      #pragma unroll
      for (int mi = 0; mi < 8; mi++)
        #pragma unroll
        for (int ni = 0; ni < 4; ni++)
          acc[mi][ni] = __builtin_amdgcn_mfma_f32_16x16x32_bf16(af[mi], bfr[ni], acc[mi][ni], 0, 0, 0);
    }
  }

  // epilogue: bias + GELU, store bf16 h (guarded rows)
  const int hb = eoff + mt * 256;
  #pragma unroll
  for (int ni = 0; ni < 4; ni++) {
    const int col = n0 + (wn << 6) + ni * 16 + (lane & 15);
    const float bias = b1[e * HI + col];
    #pragma unroll
    for (int mi = 0; mi < 8; mi++) {
      #pragma unroll
      for (int rg = 0; rg < 4; rg++) {
        const int rowl = (wm << 7) + mi * 16 + ((lane >> 4) << 2) + rg;
        if (mt * 256 + rowl < cnt) {
          const float vv = gelu_f(acc[mi][ni][rg] + bias);
          hbuf[(size_t)(hb + rowl) * HI + col] = f2bf(vv);
        }
      }
    }
  }
}

// ---------- kernel 4: grouped GEMM2 + bias -> eo (or atomic scatter) ----------
// BM=128, BN=256 (D), BK=64; 256 threads, 4 waves (1m x 4n), wave tile 128x64
__global__ __launch_bounds__(256, 2) void ffn2_k(
    const unsigned short* __restrict__ hbuf, const unsigned short* __restrict__ w2t,
    const float* __restrict__ b2, float* __restrict__ out,
    const int* __restrict__ tok_list, const float* __restrict__ gate_list,
    const int* __restrict__ counts, const int* __restrict__ offsets,
    float* __restrict__ eo)
{
  const int e = blockIdx.z;
  const int cnt = counts[e];
  const int mt = blockIdx.y;
  if (mt * 128 >= cnt) return;
  const int n0 = blockIdx.x * 256;
  const int t = threadIdx.x, lane = t & 63, w = t >> 6;
  __shared__ __align__(16) unsigned short As[128 * 64];
  __shared__ __align__(16) unsigned short Bs[256 * 64];

  const int sub = lane >> 3;
  const int kc = ((lane & 7) ^ sub) * 8;
  const int eoff = offsets[e];
  const int hb = eoff + mt * 128;
  const unsigned short* baseA[4];
  const unsigned short* baseB[8];
  #pragma unroll
  for (int r = 0; r < 4; r++) {
    int row = (w << 5) + r * 8 + sub;            // 0..127 across 4 waves
    baseA[r] = hbuf + (size_t)(hb + row) * HI + kc;
  }
  #pragma unroll
  for (int r = 0; r < 8; r++) {
    int row = (w << 6) + r * 8 + sub;            // 0..255 across 4 waves
    baseB[r] = w2t + (size_t)e * DI * HI + (size_t)(n0 + row) * HI + kc;
  }

  f32x4 acc[8][4];
  const f32x4 zz = {0.f, 0.f, 0.f, 0.f};
  #pragma unroll
  for (int i = 0; i < 8; i++)
    #pragma unroll
    for (int j = 0; j < 4; j++) acc[i][j] = zz;

  const int mrow = (lane & 15);
  const int nrow = (w << 6) + (lane & 15);
  const int ksw[2] = { ((lane >> 4) ^ (lane & 7)) * 8,
                       (((lane >> 4) + 4) ^ (lane & 7)) * 8 };

  for (int k0 = 0; k0 < HI; k0 += 64) {
    __syncthreads();
    #pragma unroll
    for (int r = 0; r < 4; r++)
      async16(baseA[r] + k0, &As[((w << 5) + r * 8) * 64]);
    #pragma unroll
    for (int r = 0; r < 8; r++)
      async16(baseB[r] + k0, &Bs[((w << 6) + r * 8) * 64]);
    __syncthreads();
    #pragma unroll
    for (int kk = 0; kk < 2; kk++) {
      const int ko = ksw[kk];
      bf16x8 af[8], bfr[4];
      #pragma unroll
      for (int mi = 0; mi < 8; mi++)
        af[mi] = *(const bf16x8*)&As[(mrow + mi * 16) * 64 + ko];
      #pragma unroll
      for (int ni = 0; ni < 4; ni++)
        bfr[ni] = *(const bf16x8*)&Bs[(nrow + ni * 16) * 64 + ko];
      #pragma unroll
      for (int mi = 0; mi < 8; mi++)
        #pragma unroll
        for (int ni = 0; ni < 4; ni++)
          acc[mi][ni] = __builtin_amdgcn_mfma_f32_16x16x32_bf16(af[mi], bfr[ni], acc[mi][ni], 0, 0, 0);
    }
  }

  float bias[4];
  #pragma unroll
  for (int ni = 0; ni < 4; ni++)
    bias[ni] = b2[e * DI + n0 + (w << 6) + ni * 16 + (lane & 15)];

  if (eo) {
    #pragma unroll
    for (int mi = 0; mi < 8; mi++) {
      #pragma unroll
      for (int rg = 0; rg < 4; rg++) {
        const int rowl = mi * 16 + ((lane >> 4) << 2) + rg;
        const int gidx = mt * 128 + rowl;
        if (gidx < cnt) {
          float* erow = eo + (size_t)(hb + rowl) * DI;
          #pragma unroll
          for (int ni = 0; ni < 4; ni++) {
            const int col = n0 + (w << 6) + ni * 16 + (lane & 15);
            erow[col] = acc[mi][ni][rg] + bias[ni];
          }
        }
      }
    }
  } else {
    #pragma unroll
    for (int mi = 0; mi < 8; mi++) {
      #pragma unroll
      for (int rg = 0; rg < 4; rg++) {
        const int rowl = mi * 16 + ((lane >> 4) << 2) + rg;
        const int gidx = mt * 128 + rowl;
        if (gidx < cnt) {
          const int tok = tok_list[eoff + gidx];
          const float gte = gate_list[eoff + gidx];
          float* orow = out + (size_t)tok * DI;
          #pragma unroll
          for (int ni = 0; ni < 4; ni++) {
            const int col = n0 + (w << 6) + ni * 16 + (lane & 15);
            atomicAdd(orow + col, (acc[mi][ni][rg] + bias[ni]) * gte);
          }
        }
      }
    }
  }
}

// ---------- kernel 5: out = x + g0*eo[p0] + g1*eo[p1] ----------
__global__ __launch_bounds__(256) void combine_k(
    const float* __restrict__ x, const float* __restrict__ eo,
    const int2* __restrict__ ipos, const float2* __restrict__ gates2,
    float* __restrict__ out)
{
  const int n = blockIdx.x, t = threadIdx.x;
  const int2 pp = ipos[n];
  const float2 gg = gates2[n];
  const float4 a = ((const float4*)(x  + (size_t)n    * DI))[t];
  const float4 b = ((const float4*)(eo + (size_t)pp.x * DI))[t];
  const float4 c = ((const float4*)(eo + (size_t)pp.y * DI))[t];
  float4 r;
  r.x = a.x + gg.x * b.x + gg.y * c.x;
  r.y = a.y + gg.x * b.y + gg.y * c.y;
  r.z = a.z + gg.x * b.z + gg.y * c.z;
  r.w = a.w + gg.x * b.w + gg.y * c.w;
  ((float4*)(out + (size_t)n * DI))[t] = r;
}

// ---------- launch ----------
extern "C" void kernel_launch(void* const* d_in, const int* in_sizes, int n_in,
                              void* d_out, int out_size, void* d_ws, size_t ws_size,
                              hipStream_t stream)
{
  const float* x   = (const float*)d_in[0];
  const float* gam = (const float*)d_in[1];
  const float* bet = (const float*)d_in[2];
  const float* gw  = (const float*)d_in[3];
  const float* w1  = (const float*)d_in[4];
  const float* b1  = (const float*)d_in[5];
  const float* w2  = (const float*)d_in[6];
  const float* b2  = (const float*)d_in[7];
  float* out = (float*)d_out;

  char* ws = (char*)d_ws;
  int*    counts = (int*)(ws + 0);
  int*    offs   = (int*)(ws + 64);
  int*    pairs  = (int*)(ws + 1024);
  float2* gates2 = (float2*)(ws + 20480);
  int*    tok    = (int*)(ws + 57344);
  float*  gate   = (float*)(ws + 90112);
  int2*   ipos   = (int2*)(ws + 122880);
  unsigned short* xnbf = (unsigned short*)(ws + 262656);

  float* bal_out   = out + (size_t)NI * DI;
  float* probs_out = bal_out + 1;

  // fast path layout: w1T 64MB @8651264, w2T 64MB @75760128+..., hbuf, eo
  const size_t W1T_OFF = 8651264;
  const size_t W2T_OFF = W1T_OFF + 67108864;           // 75760128
  const size_t HB_OFF  = W2T_OFF + 67108864;           // 142868992
  const size_t EO_OFF  = HB_OFF + 68157440;            // 211026432
  const size_t FAST_REQ = EO_OFF + 33554432;           // 244580864

  if (ws_size >= FAST_REQ) {
    unsigned short* w1t  = (unsigned short*)(ws + W1T_OFF);
    unsigned short* w2t  = (unsigned short*)(ws + W2T_OFF);
    unsigned short* hbuf = (unsigned short*)(ws + HB_OFF);
    float*          eo   = (float*)(ws + EO_OFF);

    prep_k<<<17408, 256, 0, stream>>>(x, gam, bet, gw, xnbf, probs_out, pairs, gates2,
                                      w1, w1t, w2, w2t);
    build_lists_k<<<1, 1024, 0, stream>>>(pairs, gates2, probs_out, counts, offs,
                                          tok, gate, ipos, bal_out);
    ffn1_k<<<dim3(HI / 256, 16, EI), 512, 0, stream>>>(xnbf, w1t, b1, hbuf, tok, counts, offs);
    ffn2_k<<<dim3(DI / 256, 32, EI), 256, 0, stream>>>(hbuf, w2t, b2, out, tok, gate, counts, offs, eo);
    combine_k<<<NI, 256, 0, stream>>>(x, eo, ipos, gates2, out);
  } else {
    // fallback: shared wT region (sequential transposes), atomic ffn2 epilogue
    unsigned short* wt   = (unsigned short*)(ws + W1T_OFF);
    unsigned short* hbuf = (unsigned short*)(ws + W2T_OFF);  // 75760128, 68157440 B

    prep_k<<<1024, 256, 0, stream>>>(x, gam, bet, gw, xnbf, probs_out, pairs, gates2,
                                     w1, wt, w2, wt);  // LN blocks only
    build_lists_k<<<1, 1024, 0, stream>>>(pairs, gates2, probs_out, counts, offs,
                                          tok, gate, ipos, bal_out);
    transpose_cvt_k<<<dim3(HI / 64, DI / 64, EI), 256, 0, stream>>>(w1, wt, DI, HI);
    copy_x_k<<<(NI * DI / 4) / 256, 256, 0, stream>>>(x, out);
    ffn1_k<<<dim3(HI / 256, 16, EI), 512, 0, stream>>>(xnbf, wt, b1, hbuf, tok, counts, offs);
    transpose_cvt_k<<<dim3(DI / 64, HI / 64, EI), 256, 0, stream>>>(w2, wt, HI, DI);
    ffn2_k<<<dim3(DI / 256, 32, EI), 256, 0, stream>>>(hbuf, wt, b2, out, tok, gate, counts, offs,
                                                       (float*)nullptr);
  }
}